// Round 1
// baseline (11.200 us; speedup 1.0000x reference)
//
#include <hip/hip_runtime.h>

// Hierarchical softmax loss, collapsed form:
//   out = (1/B) * sum_b sum_{t=0..14} softplus( bit_t ? s_t : -s_t )
// where s_t = scores[b, idx_t - 2], idx_0 = 2, idx_{t+1} = bit_t ? 2*idx_t : 2*idx_t - 1,
// bits taken MSB-first from class_indices[b] (15 bits since V = 32768).
// Index chain depends only on the class index -> all 15 gathers are independent.

#define B_ROWS   2048
#define V_COLS   32768
#define CODE_LEN 15

__device__ __forceinline__ float softplus_f(float x) {
    // -log(sigmoid(-x)) = log(1 + e^x) = max(x,0) + log1p(e^{-|x|})
    return fmaxf(x, 0.0f) + log1pf(expf(-fabsf(x)));
}

__global__ void hsm_partial_kernel(const float* __restrict__ scores,
                                   const int* __restrict__ class_indices,
                                   float* __restrict__ partials) {
    const int b = blockIdx.x * blockDim.x + threadIdx.x;
    float acc = 0.0f;
    if (b < B_ROWS) {
        const int ci = class_indices[b];
        const float* row = scores + (size_t)b * V_COLS;
        int idx = 2;
#pragma unroll
        for (int shift = CODE_LEN - 1; shift >= 0; --shift) {
            const int bit = (ci >> shift) & 1;
            const float s = row[idx - 2];
            acc += softplus_f(bit ? s : -s);
            idx = bit ? (2 * idx) : (2 * idx - 1);
        }
    }
    // one wave (64 lanes) per block: butterfly-free down-shuffle reduce
#pragma unroll
    for (int off = 32; off > 0; off >>= 1)
        acc += __shfl_down(acc, off);
    if (threadIdx.x == 0)
        partials[blockIdx.x] = acc;
}

__global__ void hsm_final_kernel(const float* __restrict__ partials,
                                 float* __restrict__ out,
                                 int n_partials) {
    float acc = (threadIdx.x < n_partials) ? partials[threadIdx.x] : 0.0f;
#pragma unroll
    for (int off = 32; off > 0; off >>= 1)
        acc += __shfl_down(acc, off);
    if (threadIdx.x == 0)
        out[0] = acc * (1.0f / (float)B_ROWS);
}

extern "C" void kernel_launch(void* const* d_in, const int* in_sizes, int n_in,
                              void* d_out, int out_size, void* d_ws, size_t ws_size,
                              hipStream_t stream) {
    const float* scores        = (const float*)d_in[0];
    const int*   class_indices = (const int*)d_in[1];
    float*       out           = (float*)d_out;
    float*       partials      = (float*)d_ws;

    const int threads = 64;                    // one wave per block
    const int blocks  = B_ROWS / threads;      // 32

    hsm_partial_kernel<<<blocks, threads, 0, stream>>>(scores, class_indices, partials);
    hsm_final_kernel<<<1, 64, 0, stream>>>(partials, out, blocks);
}